// Round 11
// baseline (275.354 us; speedup 1.0000x reference)
//
#include <hip/hip_runtime.h>
#include <hip/hip_bf16.h>

typedef __bf16 bf16x8 __attribute__((ext_vector_type(8)));
typedef __bf16 bf16x4 __attribute__((ext_vector_type(4)));
typedef short  s16x4  __attribute__((ext_vector_type(4)));
typedef float  f32x4  __attribute__((ext_vector_type(4)));

#define MFMA32(a, b, c) __builtin_amdgcn_mfma_f32_16x16x32_bf16((a), (b), (c), 0, 0, 0)
#define MFMA16K(a, b, c) __builtin_amdgcn_mfma_f32_16x16x16bf16_1k((a), (b), (c), 0, 0, 0)

#if __has_builtin(__builtin_amdgcn_exp2f)
#define EXP2F(x) __builtin_amdgcn_exp2f(x)
#else
#define EXP2F(x) __expf(0.6931471805599453f * (x))
#endif

#define SPLIT 8
// BS=4, C=128, L=4096, D=64. Q pre-scaled by 0.125*log2(e): softmax in base 2.
// Fixed-bound softmax: p = 2^(s - BBOUND); the 2^(m-B) factor cancels in the
// final normalization. BBOUND folded into QK MFMA accumulator init.
#define QSCALE 0.18033688011112042f
#define BBOUND 12.0f

// K workspace layout (MFMA-permuted, per 64-key tile contiguous 8 KB):
//   Kp[b][kt][nt][half][quad][l15][i]   (key = nt*16+l15, d = half*32+quad*8+i)
// -> attn A-fragment load = base + nt*1024 + half*512 + lane*8 (coalesced 1KB).
// V workspace layout (fragment-major for the PV 16x16x16 A-operand):
//   Vp3[b][kt][mt][kc8][lane=(quad,l15)][i]  (i<4: key=32*kc8+4*quad+i,
//   i>=4: key=32*kc8+16+4*quad+(i-4); d = mt*16+l15)
// -> attn V-fragment load = base + mt*1024 + kc8*512 + lane*8 (coalesced 1KB).
// Partial-O layout (fragment-major, coalesced 512B stores):
//   Ops[(split*4+b)*256+qb][mt][lane=(quad,l15)][r]  = ctx_partial[q=qb*16+l15]
//   [d=mt*16+quad*4+r], bf16.
// => the attention K-loop touches NO LDS and has NO barriers; occupancy is
//    the lever (launch_bounds(256,8), SPLIT=8 -> 8 blocks/CU).

// ---------------------------------------------------------------------------
// Kernel 1: QKV projection, bf16 MFMA. grid = 1024 (b x 256 tiles of 16 tok).
// Q bf16 [b][l][64]; K MFMA-permuted; V fragment-major (Vp3).
// ---------------------------------------------------------------------------
__global__ __launch_bounds__(256) void qkv_kernel(
    const float* __restrict__ inpt,
    const float* __restrict__ Wq, const float* __restrict__ bq,
    const float* __restrict__ Wk, const float* __restrict__ bk,
    const float* __restrict__ Wv, const float* __restrict__ bv,
    __bf16* __restrict__ Qws, __bf16* __restrict__ Kws, __bf16* __restrict__ VTws)
{
    __shared__ __align__(16) __bf16 xT[16 * 140];   // [tok][c]
    __shared__ __align__(16) __bf16 os[16 * 144];   // [tok][qk-out 0..127]
    const int bid = blockIdx.x;
    const int b   = bid >> 8;
    const int l0  = (bid & 255) << 4;               // 16 tokens
    const int t   = threadIdx.x;

    // stage x^T: thread (c = t>>1, half = t&1) loads 8 floats of row c
    {
        const int c = t >> 1, half = t & 1;
        const float* xin = inpt + ((size_t)(b * 128 + c)) * 4096 + l0 + half * 8;
        float4 v0 = *(const float4*)xin;
        float4 v1 = *(const float4*)(xin + 4);
        const int tok0 = half * 8;
        xT[(tok0 + 0) * 140 + c] = (__bf16)v0.x;
        xT[(tok0 + 1) * 140 + c] = (__bf16)v0.y;
        xT[(tok0 + 2) * 140 + c] = (__bf16)v0.z;
        xT[(tok0 + 3) * 140 + c] = (__bf16)v0.w;
        xT[(tok0 + 4) * 140 + c] = (__bf16)v1.x;
        xT[(tok0 + 5) * 140 + c] = (__bf16)v1.y;
        xT[(tok0 + 6) * 140 + c] = (__bf16)v1.z;
        xT[(tok0 + 7) * 140 + c] = (__bf16)v1.w;
    }
    __syncthreads();

    const int w    = t >> 6;
    const int lane = t & 63;
    const int quad = lane >> 4;
    const int l15  = lane & 15;

    f32x4 acc[3];
    #pragma unroll
    for (int j = 0; j < 3; ++j)
        #pragma unroll
        for (int r = 0; r < 4; ++r) acc[j][r] = 0.f;

    #pragma unroll
    for (int ks = 0; ks < 4; ++ks) {
        bf16x8 af = *(const bf16x8*)&xT[l15 * 140 + ks * 32 + quad * 8];
        #pragma unroll
        for (int j = 0; j < 3; ++j) {
            const int wn   = w * 3 + j;                 // n-tile 0..11
            const int msel = wn >> 2;                   // 0=Q 1=K 2=V
            const float* W = (msel == 0) ? Wq : ((msel == 1) ? Wk : Wv);
            const float* Wp = W + ((wn & 3) * 16 + l15) * 128 + ks * 32 + quad * 8;
            float4 wa = *(const float4*)Wp;
            float4 wb = *(const float4*)(Wp + 4);
            bf16x8 bf;
            bf[0] = (__bf16)wa.x; bf[1] = (__bf16)wa.y;
            bf[2] = (__bf16)wa.z; bf[3] = (__bf16)wa.w;
            bf[4] = (__bf16)wb.x; bf[5] = (__bf16)wb.y;
            bf[6] = (__bf16)wb.z; bf[7] = (__bf16)wb.w;
            acc[j] = MFMA32(af, bf, acc[j]);            // D[m=tok][n=out]
        }
    }

    // epilogue: D rows (quad*4+r) = token, col l15 = output within n-tile
    #pragma unroll
    for (int j = 0; j < 3; ++j) {
        const int wn   = w * 3 + j;
        const int msel = wn >> 2;
        const int o0   = (wn & 3) * 16;
        const float* bb = (msel == 0) ? bq : ((msel == 1) ? bk : bv);
        float bias = bb[o0 + l15];
        if (msel < 2) {
            // Q at cols [0,64), K at cols [64,128) of os
            const float scl = (msel == 0) ? QSCALE : 1.0f;
            const int oc = wn * 16 + l15;               // 0..127
            #pragma unroll
            for (int r = 0; r < 4; ++r)
                os[(quad * 4 + r) * 144 + oc] = (__bf16)((acc[j][r] + bias) * scl);
        } else {
            // Vp3 store: token = l0 + quad*4 + r; d = o0 + l15.
            // mt = wn&3, kc8 = (l0>>5)&1, i2 = r + ((l0>>4)&1)*4,
            // lane_v = quad*16 + l15 (quad of token == quad).
            const int mt  = wn & 3;
            const int kc8 = (l0 >> 5) & 1;
            const int i2b = ((l0 >> 4) & 1) * 4;
            bf16x4 v;
            #pragma unroll
            for (int r = 0; r < 4; ++r) v[r] = (__bf16)(acc[j][r] + bias);
            *(bf16x4*)(VTws + (size_t)b * 262144 + (l0 >> 6) * 4096
                       + mt * 1024 + kc8 * 512 + (quad * 16 + l15) * 8 + i2b) = v;
        }
    }
    __syncthreads();

    // Q store coalesced [l][64]; K store to the MFMA-permuted tile layout.
    {
        const int tok = t >> 4, c = t & 15;
        bf16x8 v = *(const bf16x8*)&os[tok * 144 + c * 8];
        if (c < 8) {
            *(bf16x8*)(Qws + ((size_t)(b * 4096 + l0 + tok)) * 64 + c * 8) = v;
        } else {
            const int d8 = c - 8;                       // d = d8*8 .. +7
            __bf16* dst = Kws + (size_t)b * 262144
                + (l0 >> 6) * 4096            // tile
                + ((l0 >> 4) & 3) * 1024      // nt subtile
                + (d8 >> 2) * 512             // half = d>>5
                + (d8 & 3) * 128              // quad = (d>>3)&3
                + tok * 8;                    // l15 = key&15
            *(bf16x8*)dst = v;
        }
    }
}

// ---------------------------------------------------------------------------
// Kernel 2: flash attention, split-K, fixed-bound softmax. ZERO LDS, ZERO
// barriers: K and V fragments load directly from global in fragment-major
// layouts (coalesced 1KB instructions; 4 waves/block share tiles via L1).
// Occupancy is the lever: launch_bounds(256,8) targets <=64 VGPR -> 8
// waves/SIMD; grid = SPLIT(8) x 256 = 2048 -> 8 blocks/CU.
// Partial ctx stored bf16 fragment-major (coalesced 512B stores).
// ---------------------------------------------------------------------------
__global__ __launch_bounds__(256, 8) void attn_kernel(
    const __bf16* __restrict__ Qws, const __bf16* __restrict__ Kws,
    const __bf16* __restrict__ VTws,
    __bf16* __restrict__ Ops, float* __restrict__ Lws)
{
    const int bid   = blockIdx.x;
    const int split = bid >> 8;                      // 0..7
    const int qt    = bid & 255;
    const int b  = qt >> 6;
    const int l0 = (qt & 63) << 6;
    const int t    = threadIdx.x;
    const int w    = t >> 6;
    const int lane = t & 63;
    const int quad = lane >> 4;
    const int l15  = lane & 15;

    // Q fragments (q = l15), pre-scaled by 0.125*log2e
    const __bf16* qptr = Qws + ((size_t)(b * 4096 + l0 + w * 16 + l15)) * 64 + quad * 8;
    bf16x8 qf0 = *(const bf16x8*)qptr;
    bf16x8 qf1 = *(const bf16x8*)(qptr + 32);

    f32x4 cfr[4];
    #pragma unroll
    for (int mt = 0; mt < 4; ++mt)
        #pragma unroll
        for (int r = 0; r < 4; ++r) cfr[mt][r] = 0.f;
    float l_run = 0.f;

    // per-lane fragment base pointers (split region: 8 tiles of 4096 elems)
    const __bf16* Kt = Kws  + ((size_t)b << 18) + (size_t)split * 8 * 4096 + lane * 8;
    const __bf16* Vt = VTws + ((size_t)b << 18) + (size_t)split * 8 * 4096 + lane * 8;

    union B4 { bf16x4 h; s16x4 s; };
    union V8 { bf16x8 v; s16x4 q[2]; };

    for (int kt = 0; kt < 8; ++kt) {
        const __bf16* Kp = Kt + kt * 4096;
        const __bf16* Vp = Vt + kt * 4096;

        // ---- QK^T (A=K direct-global, B=Q), C init = -BBOUND, p=exp2(s) ---
        B4 pk[4];                      // P in C-layout == B-layout of 16x16x16
        float ps[4];
        #pragma unroll
        for (int nt = 0; nt < 4; ++nt) {
            bf16x8 kf0 = *(const bf16x8*)(Kp + nt * 1024);
            bf16x8 kf1 = *(const bf16x8*)(Kp + nt * 1024 + 512);
            f32x4 a = {-BBOUND, -BBOUND, -BBOUND, -BBOUND};
            a = MFMA32(kf0, qf0, a);
            a = MFMA32(kf1, qf1, a);
            float p0 = EXP2F(a[0]), p1 = EXP2F(a[1]);
            float p2 = EXP2F(a[2]), p3 = EXP2F(a[3]);
            pk[nt].h[0] = (__bf16)p0; pk[nt].h[1] = (__bf16)p1;
            pk[nt].h[2] = (__bf16)p2; pk[nt].h[3] = (__bf16)p3;
            ps[nt] = (p0 + p1) + (p2 + p3);
        }
        float psum = (ps[0] + ps[1]) + (ps[2] + ps[3]);
        psum += __shfl_xor(psum, 16);
        psum += __shfl_xor(psum, 32);
        l_run += psum;

        // ---- PV: ctx^T += V^T · P^T (V direct-global fragment-major) ------
        #pragma unroll
        for (int kc8 = 0; kc8 < 2; ++kc8) {
            #pragma unroll
            for (int mt = 0; mt < 4; ++mt) {
                V8 vv;
                vv.v = *(const bf16x8*)(Vp + mt * 1024 + kc8 * 512);
                cfr[mt] = MFMA16K(vv.q[0], pk[2 * kc8 + 0].s, cfr[mt]);
                cfr[mt] = MFMA16K(vv.q[1], pk[2 * kc8 + 1].s, cfr[mt]);
            }
        }
    }

    // epilogue: partial ctx bf16, fragment-major, coalesced 512B stores.
    {
        const int qb = (l0 >> 4) + w;                  // 16-token slab index
        __bf16* ob = Ops + (((size_t)((split * 4 + b) * 256 + qb)) << 10) + lane * 4;
        #pragma unroll
        for (int mt = 0; mt < 4; ++mt) {
            bf16x4 v;
            #pragma unroll
            for (int r = 0; r < 4; ++r) v[r] = (__bf16)cfr[mt][r];
            *(bf16x4*)(ob + mt * 256) = v;
        }
        if (quad == 0) Lws[(split * 4 + b) * 4096 + l0 + w * 16 + l15] = l_run;
    }
}

// ---------------------------------------------------------------------------
// Kernel 3: split-combine (pure sum, bf16 fragment-major partials) + output
// projection (bf16 MFMA) + bias + residual. grid = 1024 (b x 256 x 16 tok).
// ---------------------------------------------------------------------------
__global__ __launch_bounds__(256) void outproj_kernel(
    const float* __restrict__ inpt,
    const __bf16* __restrict__ Ops, const float* __restrict__ Lws,
    const float* __restrict__ Wo, const float* __restrict__ bo,
    float* __restrict__ out)
{
    __shared__ __align__(16) __bf16 cx[16 * 72];    // combined ctx [tok][d]
    const int bid = blockIdx.x;
    const int b   = bid >> 8;
    const int qb  = bid & 255;
    const int l0  = qb << 4;
    const int t   = threadIdx.x;

    // combine: thread (token = t>>4, d4 = (t&15)*4); fragment-major reads
    {
        const int token = t >> 4, d4 = (t & 15) << 2;
        const int rowb  = b * 4096 + l0 + token;
        float denom = 0.f;
        #pragma unroll
        for (int s = 0; s < SPLIT; ++s) denom += Lws[s * 16384 + rowb];
        const float inv = 1.f / denom;
        const int mt     = d4 >> 4;
        const int lane_f = ((d4 >> 2) & 3) * 16 + token;
        float ax = 0.f, ay = 0.f, az = 0.f, aw = 0.f;
        #pragma unroll
        for (int s = 0; s < SPLIT; ++s) {
            const bf16x4 v = *(const bf16x4*)(Ops
                + (((size_t)((s * 4 + b) * 256 + qb)) << 10) + mt * 256 + lane_f * 4);
            ax += (float)v[0]; ay += (float)v[1];
            az += (float)v[2]; aw += (float)v[3];
        }
        bf16x4 pv;
        pv[0] = (__bf16)(ax * inv); pv[1] = (__bf16)(ay * inv);
        pv[2] = (__bf16)(az * inv); pv[3] = (__bf16)(aw * inv);
        *(bf16x4*)&cx[token * 72 + d4] = pv;
    }
    __syncthreads();

    const int w    = t >> 6;
    const int lane = t & 63;
    const int quad = lane >> 4;
    const int l15  = lane & 15;

    f32x4 acc[2];
    #pragma unroll
    for (int mi = 0; mi < 2; ++mi)
        #pragma unroll
        for (int r = 0; r < 4; ++r) acc[mi][r] = 0.f;

    #pragma unroll
    for (int ks = 0; ks < 2; ++ks) {
        bf16x8 bfrag = *(const bf16x8*)&cx[l15 * 72 + ks * 32 + quad * 8];  // B[n=tok][k=d]
        #pragma unroll
        for (int mi = 0; mi < 2; ++mi) {
            const int crow = (w * 2 + mi) * 16 + l15;
            const float* Wp = Wo + crow * 64 + ks * 32 + quad * 8;
            float4 wa = *(const float4*)Wp;
            float4 wb = *(const float4*)(Wp + 4);
            bf16x8 afrag;
            afrag[0] = (__bf16)wa.x; afrag[1] = (__bf16)wa.y;
            afrag[2] = (__bf16)wa.z; afrag[3] = (__bf16)wa.w;
            afrag[4] = (__bf16)wb.x; afrag[5] = (__bf16)wb.y;
            afrag[6] = (__bf16)wb.z; afrag[7] = (__bf16)wb.w;
            acc[mi] = MFMA32(afrag, bfrag, acc[mi]);     // D[m=c][n=tok]
        }
    }

    // epilogue: rows (quad*4+r) = c offset, col l15 = token
    #pragma unroll
    for (int mi = 0; mi < 2; ++mi) {
        #pragma unroll
        for (int r = 0; r < 4; ++r) {
            const int c = (w * 2 + mi) * 16 + quad * 4 + r;
            const size_t addr = ((size_t)(b * 128 + c)) * 4096 + l0 + l15;
            out[addr] = inpt[addr] + bo[c] + acc[mi][r];
        }
    }
}

// ---------------------------------------------------------------------------
extern "C" void kernel_launch(void* const* d_in, const int* in_sizes, int n_in,
                              void* d_out, int out_size, void* d_ws, size_t ws_size,
                              hipStream_t stream)
{
    const float* inpt = (const float*)d_in[0];
    const float* Wq   = (const float*)d_in[1];
    const float* bq   = (const float*)d_in[2];
    const float* Wk   = (const float*)d_in[3];
    const float* bk   = (const float*)d_in[4];
    const float* Wv   = (const float*)d_in[5];
    const float* bv   = (const float*)d_in[6];
    const float* Wo   = (const float*)d_in[7];
    const float* bo   = (const float*)d_in[8];
    float* out = (float*)d_out;

    char* ws = (char*)d_ws;
    const size_t MB = (size_t)1 << 20;
    __bf16* Qws  = (__bf16*)(ws + 0 * MB);
    __bf16* Kws  = (__bf16*)(ws + 2 * MB);         // MFMA-permuted tile layout
    __bf16* VTws = (__bf16*)(ws + 4 * MB);         // fragment-major (Vp3)
    __bf16* Ops  = (__bf16*)(ws + 6 * MB);         // SPLIT(8) x 2.1MB = 16.8 MB
    float*  Lws  = (float*)(ws + 24 * MB);         // 512 KB

    qkv_kernel<<<1024, 256, 0, stream>>>(inpt, Wq, bq, Wk, bk, Wv, bv, Qws, Kws, VTws);
    attn_kernel<<<SPLIT * 256, 256, 0, stream>>>(Qws, Kws, VTws, Ops, Lws);
    outproj_kernel<<<1024, 256, 0, stream>>>(inpt, Ops, Lws, Wo, bo, out);
}

// Round 12
// 126.455 us; speedup vs baseline: 2.1775x; 2.1775x over previous
//
#include <hip/hip_runtime.h>
#include <hip/hip_bf16.h>

typedef __bf16 bf16x8 __attribute__((ext_vector_type(8)));
typedef __bf16 bf16x4 __attribute__((ext_vector_type(4)));
typedef short  s16x4  __attribute__((ext_vector_type(4)));
typedef float  f32x4  __attribute__((ext_vector_type(4)));

#define MFMA32(a, b, c) __builtin_amdgcn_mfma_f32_16x16x32_bf16((a), (b), (c), 0, 0, 0)
#define MFMA16K(a, b, c) __builtin_amdgcn_mfma_f32_16x16x16bf16_1k((a), (b), (c), 0, 0, 0)

#if __has_builtin(__builtin_amdgcn_exp2f)
#define EXP2F(x) __builtin_amdgcn_exp2f(x)
#else
#define EXP2F(x) __expf(0.6931471805599453f * (x))
#endif

// async global->LDS, 16B per lane. LDS dest must be wave-uniform base.
#define GL16(G, L)                                                            \
    __builtin_amdgcn_global_load_lds(                                         \
        (const __attribute__((address_space(1))) void*)(G),                   \
        (__attribute__((address_space(3))) void*)(L), 16, 0, 0)

#define SPLIT 8
// BS=4, C=128, L=4096, D=64. Q pre-scaled by 0.125*log2(e): softmax in base 2.
// Fixed-bound softmax: p = 2^(s - BBOUND); the 2^(m-B) factor cancels in the
// final normalization. BBOUND folded into QK MFMA accumulator init.
#define QSCALE 0.18033688011112042f
#define BBOUND 12.0f

// K workspace layout (MFMA-permuted, per 64-key tile contiguous 8 KB):
//   Kp[b][kt][nt][half][quad][l15][i]   (key = nt*16+l15, d = half*32+quad*8+i)
// -> attn's A-fragment load for subtile nt is base + nt*1024 + half*512 +
//    lane*8: one fully-coalesced 1KB instruction.
// V workspace layout (permuted, per 64-key tile contiguous 8 KB):
//   Vp[b][kt][d][quad][kc][i]  (quad=key>>2&3, kc=key>>4, i=key&3)
// so attn lane (d, quad) reads its 16 V elements for all 4 kc-blocks as two
// contiguous b128 chunks (chunk index 2*quad+kc8, kc8 = kc>>1).
// R11 lesson: never force launch_bounds below live-state (spill catastrophe)
// and never drop LDS V-reuse. Occupancy comes from grid: SPLIT=8 -> 2048
// blocks = 8/CU; attn's natural VGPR (~60) already allows 8 waves/SIMD.

// ---------------------------------------------------------------------------
// Kernel 1: QKV projection, bf16 MFMA. grid = 1024 (b x 256 tiles of 16 tok).
// Q bf16 [b][l][64] (LDS bounce -> coalesced 16B stores); K in permuted tile
// layout (LDS bounce -> 16B stores in 64B segments); V permuted (8B stores).
// ---------------------------------------------------------------------------
__global__ __launch_bounds__(256) void qkv_kernel(
    const float* __restrict__ inpt,
    const float* __restrict__ Wq, const float* __restrict__ bq,
    const float* __restrict__ Wk, const float* __restrict__ bk,
    const float* __restrict__ Wv, const float* __restrict__ bv,
    __bf16* __restrict__ Qws, __bf16* __restrict__ Kws, __bf16* __restrict__ VTws)
{
    __shared__ __align__(16) __bf16 xT[16 * 140];   // [tok][c]
    __shared__ __align__(16) __bf16 os[16 * 144];   // [tok][qk-out 0..127]
    const int bid = blockIdx.x;
    const int b   = bid >> 8;
    const int l0  = (bid & 255) << 4;               // 16 tokens
    const int t   = threadIdx.x;

    // stage x^T: thread (c = t>>1, half = t&1) loads 8 floats of row c
    {
        const int c = t >> 1, half = t & 1;
        const float* xin = inpt + ((size_t)(b * 128 + c)) * 4096 + l0 + half * 8;
        float4 v0 = *(const float4*)xin;
        float4 v1 = *(const float4*)(xin + 4);
        const int tok0 = half * 8;
        xT[(tok0 + 0) * 140 + c] = (__bf16)v0.x;
        xT[(tok0 + 1) * 140 + c] = (__bf16)v0.y;
        xT[(tok0 + 2) * 140 + c] = (__bf16)v0.z;
        xT[(tok0 + 3) * 140 + c] = (__bf16)v0.w;
        xT[(tok0 + 4) * 140 + c] = (__bf16)v1.x;
        xT[(tok0 + 5) * 140 + c] = (__bf16)v1.y;
        xT[(tok0 + 6) * 140 + c] = (__bf16)v1.z;
        xT[(tok0 + 7) * 140 + c] = (__bf16)v1.w;
    }
    __syncthreads();

    const int w    = t >> 6;
    const int lane = t & 63;
    const int quad = lane >> 4;
    const int l15  = lane & 15;

    f32x4 acc[3];
    #pragma unroll
    for (int j = 0; j < 3; ++j)
        #pragma unroll
        for (int r = 0; r < 4; ++r) acc[j][r] = 0.f;

    #pragma unroll
    for (int ks = 0; ks < 4; ++ks) {
        bf16x8 af = *(const bf16x8*)&xT[l15 * 140 + ks * 32 + quad * 8];
        #pragma unroll
        for (int j = 0; j < 3; ++j) {
            const int wn   = w * 3 + j;                 // n-tile 0..11
            const int msel = wn >> 2;                   // 0=Q 1=K 2=V
            const float* W = (msel == 0) ? Wq : ((msel == 1) ? Wk : Wv);
            const float* Wp = W + ((wn & 3) * 16 + l15) * 128 + ks * 32 + quad * 8;
            float4 wa = *(const float4*)Wp;
            float4 wb = *(const float4*)(Wp + 4);
            bf16x8 bf;
            bf[0] = (__bf16)wa.x; bf[1] = (__bf16)wa.y;
            bf[2] = (__bf16)wa.z; bf[3] = (__bf16)wa.w;
            bf[4] = (__bf16)wb.x; bf[5] = (__bf16)wb.y;
            bf[6] = (__bf16)wb.z; bf[7] = (__bf16)wb.w;
            acc[j] = MFMA32(af, bf, acc[j]);            // D[m=tok][n=out]
        }
    }

    // epilogue: D rows (quad*4+r) = token, col l15 = output within n-tile
    #pragma unroll
    for (int j = 0; j < 3; ++j) {
        const int wn   = w * 3 + j;
        const int msel = wn >> 2;
        const int o0   = (wn & 3) * 16;
        const float* bb = (msel == 0) ? bq : ((msel == 1) ? bk : bv);
        float bias = bb[o0 + l15];
        if (msel < 2) {
            // Q at cols [0,64), K at cols [64,128) of os
            const float scl = (msel == 0) ? QSCALE : 1.0f;
            const int oc = wn * 16 + l15;               // 0..127
            #pragma unroll
            for (int r = 0; r < 4; ++r)
                os[(quad * 4 + r) * 144 + oc] = (__bf16)((acc[j][r] + bias) * scl);
        } else {
            // permuted V store: token l0+quad*4+r -> tile kt, kc fixed per
            // block, quad_v == quad, i == r.
            const int d  = o0 + l15;
            const int kt = l0 >> 6;
            const int kc = (l0 >> 4) & 3;
            bf16x4 v;
            #pragma unroll
            for (int r = 0; r < 4; ++r) v[r] = (__bf16)(acc[j][r] + bias);
            *(bf16x4*)(VTws + (size_t)b * 262144 + kt * 4096
                       + d * 64 + quad * 16 + kc * 4) = v;
        }
    }
    __syncthreads();

    // Q store coalesced [l][64]; K store to the MFMA-permuted tile layout.
    // thread t -> token tok = t>>4, 16B chunk c = t&15.
    {
        const int tok = t >> 4, c = t & 15;
        bf16x8 v = *(const bf16x8*)&os[tok * 144 + c * 8];
        if (c < 8) {
            *(bf16x8*)(Qws + ((size_t)(b * 4096 + l0 + tok)) * 64 + c * 8) = v;
        } else {
            const int d8 = c - 8;                       // d = d8*8 .. +7
            __bf16* dst = Kws + (size_t)b * 262144
                + (l0 >> 6) * 4096            // tile
                + ((l0 >> 4) & 3) * 1024      // nt subtile
                + (d8 >> 2) * 512             // half = d>>5
                + (d8 & 3) * 128              // quad = (d>>3)&3
                + tok * 8;                    // l15 = key&15
            *(bf16x8*)dst = v;
        }
    }
}

// ---------------------------------------------------------------------------
// Kernel 2: flash attention, split-K, fixed-bound softmax (no online max).
// K fragments direct from global in MFMA-permuted layout (coalesced 1KB
// instructions, prefetched one tile ahead into a second register set; 4
// waves/block share the tile -> L1 hits). LDS stages only V (double-buffered
// global_load_lds, XOR-swizzled, b128 reads). PV via mfma 16x16x16bf16_1k
// (B-layout == QK C-layout; no P transpose). Partial ctx bf16 via LDS
// transpose -> coalesced 16B full-line stores.
// grid = SPLIT(8) x 256 = 2048 -> 8 blocks/CU (occupancy is the lever).
// ---------------------------------------------------------------------------
__global__ __launch_bounds__(256, 4) void attn_kernel(
    const __bf16* __restrict__ Qws, const __bf16* __restrict__ Kws,
    const __bf16* __restrict__ VTws,
    __bf16* __restrict__ Ops, float* __restrict__ Lws)
{
    // V only: slots of 16B, [d][chunk^(d&7)] (permuted layout), 2 x 8 KB
    __shared__ __align__(16) __bf16 sbuf[2][4096];

    const int bid   = blockIdx.x;
    const int split = bid >> 8;                      // 0..7
    const int qt    = bid & 255;
    const int b  = qt >> 6;
    const int l0 = (qt & 63) << 6;
    const int t    = threadIdx.x;
    const int w    = t >> 6;
    const int lane = t & 63;
    const int quad = lane >> 4;
    const int l15  = lane & 15;

    // Q fragments (q = l15), pre-scaled by 0.125*log2e
    const __bf16* qptr = Qws + ((size_t)(b * 4096 + l0 + w * 16 + l15)) * 64 + quad * 8;
    bf16x8 qf0 = *(const bf16x8*)qptr;
    bf16x8 qf1 = *(const bf16x8*)(qptr + 32);

    f32x4 cfr[4];
    #pragma unroll
    for (int mt = 0; mt < 4; ++mt)
        #pragma unroll
        for (int r = 0; r < 4; ++r) cfr[mt][r] = 0.f;
    float l_run = 0.f;

    // hoisted V LDS element offsets (loop-invariant across tiles)
    int voff[8];
    #pragma unroll
    for (int mt = 0; mt < 4; ++mt) {
        const int d = mt * 16 + l15;
        #pragma unroll
        for (int kc8 = 0; kc8 < 2; ++kc8)
            voff[kc8 * 4 + mt] = d * 64 + (((2 * quad + kc8) ^ (d & 7)) * 8);
    }

    // V staging source pointer (swizzled 16B chunks); split region = 8 tiles
    const uint4* Vg = (const uint4*)(VTws + ((size_t)b << 18));
    const int rw = t >> 3, cw = (t & 7) ^ ((t >> 3) & 7);
    const uint4* vp = Vg + rw * 8 + cw + split * 4096;

    // K direct-global, permuted layout: per-lane offset lane*8 (coalesced)
    const __bf16* Kgl = Kws + ((size_t)b << 18)
                      + (size_t)(split * 8) * 4096 + lane * 8;

    union B4 { bf16x4 h; s16x4 s; };
    union V8 { bf16x8 v; s16x4 q[2]; };

    auto stageV = [&](__bf16* Bb) {
        GL16(vp,       Bb +        w * 512);
        GL16(vp + 256, Bb + 2048 + w * 512);
        vp += 512;
    };

    bf16x8 kfA[4][2], kfB[4][2];
    auto loadK = [&](bf16x8 (*kf)[2], int kt) {
        const __bf16* p = Kgl + (size_t)kt * 4096;
        #pragma unroll
        for (int nt = 0; nt < 4; ++nt) {
            kf[nt][0] = *(const bf16x8*)(p + nt * 1024);
            kf[nt][1] = *(const bf16x8*)(p + nt * 1024 + 512);
        }
    };

    auto tile_step = [&](const __bf16* __restrict__ B, bf16x8 (*kf)[2]) {
        // ---- QK^T (A=K from regs, B=Q), C init = -BBOUND, p = exp2(s) -----
        B4 pk[4];                      // P in C-layout == B-layout of 16x16x16
        float ps[4];
        #pragma unroll
        for (int nt = 0; nt < 4; ++nt) {
            f32x4 a = {-BBOUND, -BBOUND, -BBOUND, -BBOUND};
            a = MFMA32(kf[nt][0], qf0, a);
            a = MFMA32(kf[nt][1], qf1, a);
            float p0 = EXP2F(a[0]), p1 = EXP2F(a[1]);
            float p2 = EXP2F(a[2]), p3 = EXP2F(a[3]);
            pk[nt].h[0] = (__bf16)p0; pk[nt].h[1] = (__bf16)p1;
            pk[nt].h[2] = (__bf16)p2; pk[nt].h[3] = (__bf16)p3;
            ps[nt] = (p0 + p1) + (p2 + p3);
        }
        float psum = (ps[0] + ps[1]) + (ps[2] + ps[3]);
        psum += __shfl_xor(psum, 16);
        psum += __shfl_xor(psum, 32);
        l_run += psum;

        // ---- PV: ctx^T += V^T · P^T (b128 V reads, two MFMAs per read) ----
        #pragma unroll
        for (int kc8 = 0; kc8 < 2; ++kc8) {
            #pragma unroll
            for (int mt = 0; mt < 4; ++mt) {
                V8 vv;
                vv.v = *(const bf16x8*)&B[voff[kc8 * 4 + mt]];
                cfr[mt] = MFMA16K(vv.q[0], pk[2 * kc8 + 0].s, cfr[mt]);
                cfr[mt] = MFMA16K(vv.q[1], pk[2 * kc8 + 1].s, cfr[mt]);
            }
        }
    };

    // prologue: V tile 0 -> buffer 0; K frags tile 0 -> regs
    stageV(sbuf[0]);
    loadK(kfA, 0);

    for (int kt2 = 0; kt2 < 4; ++kt2) {
        __syncthreads();               // V buffer 0 ready (vmcnt drained)
        stageV(sbuf[1]);               // prefetch odd V tile
        loadK(kfB, 2 * kt2 + 1);       // prefetch odd K frags (used next step)
        tile_step(sbuf[0], kfA);
        __syncthreads();               // V buffer 1 ready
        if (kt2 < 3) {
            stageV(sbuf[0]);
            loadK(kfA, 2 * kt2 + 2);
        }
        tile_step(sbuf[1], kfB);
    }
    __syncthreads();                   // sbuf free for epilogue transpose

    // epilogue: transpose ctx through LDS so partial ctx goes out as
    // coalesced bf16 16B stores (full 128B lines per row).
    {
        __bf16* tb = (__bf16*)sbuf + w * 1088;     // 16 rows x stride 68
        #pragma unroll
        for (int mt = 0; mt < 4; ++mt) {
            bf16x4 v;
            #pragma unroll
            for (int r = 0; r < 4; ++r) v[r] = (__bf16)cfr[mt][r];
            *(bf16x4*)&tb[l15 * 68 + mt * 16 + quad * 4] = v;
        }
        const int rowbase = (split * 4 + b) * 4096 + l0 + w * 16;
        #pragma unroll
        for (int h = 0; h < 2; ++h) {
            const int chunk = lane + h * 64;       // 0..127
            const int tok = chunk >> 3, c8 = chunk & 7;
            bf16x8 v = *(const bf16x8*)&tb[tok * 68 + c8 * 8];
            *(bf16x8*)(Ops + (size_t)(rowbase + tok) * 64 + c8 * 8) = v;
        }
        if (quad == 0) Lws[rowbase + l15] = l_run;
    }
}

// ---------------------------------------------------------------------------
// Kernel 3: split-combine (pure sum, bf16 partials) + output projection
// (bf16 MFMA) + bias + residual. grid = 1024 (b x 256 x 16 tok).
// ---------------------------------------------------------------------------
__global__ __launch_bounds__(256) void outproj_kernel(
    const float* __restrict__ inpt,
    const __bf16* __restrict__ Ops, const float* __restrict__ Lws,
    const float* __restrict__ Wo, const float* __restrict__ bo,
    float* __restrict__ out)
{
    __shared__ __align__(16) __bf16 cx[16 * 72];    // combined ctx [tok][d]
    const int bid = blockIdx.x;
    const int b   = bid >> 8;
    const int l0  = (bid & 255) << 4;
    const int t   = threadIdx.x;

    // combine: thread (token = t>>4, d4 = (t&15)*4); partials sum directly
    {
        const int token = t >> 4, d4 = (t & 15) << 2;
        const int rowb  = b * 4096 + l0 + token;
        float denom = 0.f;
        #pragma unroll
        for (int s = 0; s < SPLIT; ++s) denom += Lws[s * 16384 + rowb];
        const float inv = 1.f / denom;
        float ax = 0.f, ay = 0.f, az = 0.f, aw = 0.f;
        #pragma unroll
        for (int s = 0; s < SPLIT; ++s) {
            const bf16x4 v = *(const bf16x4*)(Ops
                + ((size_t)(s * 16384 + rowb)) * 64 + d4);
            ax += (float)v[0]; ay += (float)v[1];
            az += (float)v[2]; aw += (float)v[3];
        }
        bf16x4 pv;
        pv[0] = (__bf16)(ax * inv); pv[1] = (__bf16)(ay * inv);
        pv[2] = (__bf16)(az * inv); pv[3] = (__bf16)(aw * inv);
        *(bf16x4*)&cx[token * 72 + d4] = pv;
    }
    __syncthreads();

    const int w    = t >> 6;
    const int lane = t & 63;
    const int quad = lane >> 4;
    const int l15  = lane & 15;

    f32x4 acc[2];
    #pragma unroll
    for (int mi = 0; mi < 2; ++mi)
        #pragma unroll
        for (int r = 0; r < 4; ++r) acc[mi][r] = 0.f;

    #pragma unroll
    for (int ks = 0; ks < 2; ++ks) {
        bf16x8 bfrag = *(const bf16x8*)&cx[l15 * 72 + ks * 32 + quad * 8];  // B[n=tok][k=d]
        #pragma unroll
        for (int mi = 0; mi < 2; ++mi) {
            const int crow = (w * 2 + mi) * 16 + l15;
            const float* Wp = Wo + crow * 64 + ks * 32 + quad * 8;
            float4 wa = *(const float4*)Wp;
            float4 wb = *(const float4*)(Wp + 4);
            bf16x8 afrag;
            afrag[0] = (__bf16)wa.x; afrag[1] = (__bf16)wa.y;
            afrag[2] = (__bf16)wa.z; afrag[3] = (__bf16)wa.w;
            afrag[4] = (__bf16)wb.x; afrag[5] = (__bf16)wb.y;
            afrag[6] = (__bf16)wb.z; afrag[7] = (__bf16)wb.w;
            acc[mi] = MFMA32(afrag, bfrag, acc[mi]);     // D[m=c][n=tok]
        }
    }

    // epilogue: rows (quad*4+r) = c offset, col l15 = token
    #pragma unroll
    for (int mi = 0; mi < 2; ++mi) {
        #pragma unroll
        for (int r = 0; r < 4; ++r) {
            const int c = (w * 2 + mi) * 16 + quad * 4 + r;
            const size_t addr = ((size_t)(b * 128 + c)) * 4096 + l0 + l15;
            out[addr] = inpt[addr] + bo[c] + acc[mi][r];
        }
    }
}

// ---------------------------------------------------------------------------
extern "C" void kernel_launch(void* const* d_in, const int* in_sizes, int n_in,
                              void* d_out, int out_size, void* d_ws, size_t ws_size,
                              hipStream_t stream)
{
    const float* inpt = (const float*)d_in[0];
    const float* Wq   = (const float*)d_in[1];
    const float* bq   = (const float*)d_in[2];
    const float* Wk   = (const float*)d_in[3];
    const float* bk   = (const float*)d_in[4];
    const float* Wv   = (const float*)d_in[5];
    const float* bv   = (const float*)d_in[6];
    const float* Wo   = (const float*)d_in[7];
    const float* bo   = (const float*)d_in[8];
    float* out = (float*)d_out;

    char* ws = (char*)d_ws;
    const size_t MB = (size_t)1 << 20;
    __bf16* Qws  = (__bf16*)(ws + 0 * MB);
    __bf16* Kws  = (__bf16*)(ws + 2 * MB);         // MFMA-permuted tile layout
    __bf16* VTws = (__bf16*)(ws + 4 * MB);         // permuted tile layout
    __bf16* Ops  = (__bf16*)(ws + 6 * MB);         // SPLIT(8) x 2.1MB = 16.8 MB
    float*  Lws  = (float*)(ws + 24 * MB);         // 512 KB

    qkv_kernel<<<1024, 256, 0, stream>>>(inpt, Wq, bq, Wk, bk, Wv, bv, Qws, Kws, VTws);
    attn_kernel<<<SPLIT * 256, 256, 0, stream>>>(Qws, Kws, VTws, Ops, Lws);
    outproj_kernel<<<1024, 256, 0, stream>>>(inpt, Ops, Lws, Wo, bo, out);
}

// Round 13
// 124.578 us; speedup vs baseline: 2.2103x; 1.0151x over previous
//
#include <hip/hip_runtime.h>
#include <hip/hip_bf16.h>

typedef __bf16 bf16x8 __attribute__((ext_vector_type(8)));
typedef __bf16 bf16x4 __attribute__((ext_vector_type(4)));
typedef short  s16x4  __attribute__((ext_vector_type(4)));
typedef float  f32x4  __attribute__((ext_vector_type(4)));

#define MFMA32(a, b, c) __builtin_amdgcn_mfma_f32_16x16x32_bf16((a), (b), (c), 0, 0, 0)
#define MFMA16K(a, b, c) __builtin_amdgcn_mfma_f32_16x16x16bf16_1k((a), (b), (c), 0, 0, 0)

#if __has_builtin(__builtin_amdgcn_exp2f)
#define EXP2F(x) __builtin_amdgcn_exp2f(x)
#else
#define EXP2F(x) __expf(0.6931471805599453f * (x))
#endif

// async global->LDS, 16B per lane. LDS dest must be wave-uniform base.
#define GL16(G, L)                                                            \
    __builtin_amdgcn_global_load_lds(                                         \
        (const __attribute__((address_space(1))) void*)(G),                   \
        (__attribute__((address_space(3))) void*)(L), 16, 0, 0)

#define SPLIT 4
// BS=4, C=128, L=4096, D=64. Q pre-scaled by 0.125*log2(e): softmax in base 2.
// Fixed-bound softmax: p = 2^(s - BBOUND); the 2^(m-B) factor cancels in the
// final normalization. BBOUND folded into QK MFMA accumulator init.
#define QSCALE 0.18033688011112042f
#define BBOUND 12.0f

// K workspace layout (MFMA-permuted, per 64-key tile contiguous 8 KB):
//   Kp[b][kt][nt][half][quad][l15][i]   (key = nt*16+l15, d = half*32+quad*8+i)
// -> attn's A-fragment load for subtile nt is base + nt*1024 + half*512 +
//    lane*8: one fully-coalesced 1KB instruction.
// V workspace layout (permuted, per 64-key tile contiguous 8 KB):
//   Vp[b][kt][d][quad][kc][i]  (quad=key>>2&3, kc=key>>4, i=key&3)
// so attn lane (d, quad) reads its 16 V elements for all 4 kc-blocks as two
// contiguous b128 chunks (chunk index 2*quad+kc8, kc8 = kc>>1).

// ---------------------------------------------------------------------------
// Kernel 1: QKV projection, bf16 MFMA. grid = 1024 (b x 256 tiles of 16 tok).
// Q bf16 [b][l][64] (LDS bounce -> coalesced 16B stores); K in permuted tile
// layout (LDS bounce -> 16B stores in 64B segments); V permuted (8B stores).
// ---------------------------------------------------------------------------
__global__ __launch_bounds__(256) void qkv_kernel(
    const float* __restrict__ inpt,
    const float* __restrict__ Wq, const float* __restrict__ bq,
    const float* __restrict__ Wk, const float* __restrict__ bk,
    const float* __restrict__ Wv, const float* __restrict__ bv,
    __bf16* __restrict__ Qws, __bf16* __restrict__ Kws, __bf16* __restrict__ VTws)
{
    __shared__ __align__(16) __bf16 xT[16 * 140];   // [tok][c]
    __shared__ __align__(16) __bf16 os[16 * 144];   // [tok][qk-out 0..127]
    const int bid = blockIdx.x;
    const int b   = bid >> 8;
    const int l0  = (bid & 255) << 4;               // 16 tokens
    const int t   = threadIdx.x;

    // stage x^T: thread (c = t>>1, half = t&1) loads 8 floats of row c
    {
        const int c = t >> 1, half = t & 1;
        const float* xin = inpt + ((size_t)(b * 128 + c)) * 4096 + l0 + half * 8;
        float4 v0 = *(const float4*)xin;
        float4 v1 = *(const float4*)(xin + 4);
        const int tok0 = half * 8;
        xT[(tok0 + 0) * 140 + c] = (__bf16)v0.x;
        xT[(tok0 + 1) * 140 + c] = (__bf16)v0.y;
        xT[(tok0 + 2) * 140 + c] = (__bf16)v0.z;
        xT[(tok0 + 3) * 140 + c] = (__bf16)v0.w;
        xT[(tok0 + 4) * 140 + c] = (__bf16)v1.x;
        xT[(tok0 + 5) * 140 + c] = (__bf16)v1.y;
        xT[(tok0 + 6) * 140 + c] = (__bf16)v1.z;
        xT[(tok0 + 7) * 140 + c] = (__bf16)v1.w;
    }
    __syncthreads();

    const int w    = t >> 6;
    const int lane = t & 63;
    const int quad = lane >> 4;
    const int l15  = lane & 15;

    f32x4 acc[3];
    #pragma unroll
    for (int j = 0; j < 3; ++j)
        #pragma unroll
        for (int r = 0; r < 4; ++r) acc[j][r] = 0.f;

    #pragma unroll
    for (int ks = 0; ks < 4; ++ks) {
        bf16x8 af = *(const bf16x8*)&xT[l15 * 140 + ks * 32 + quad * 8];
        #pragma unroll
        for (int j = 0; j < 3; ++j) {
            const int wn   = w * 3 + j;                 // n-tile 0..11
            const int msel = wn >> 2;                   // 0=Q 1=K 2=V
            const float* W = (msel == 0) ? Wq : ((msel == 1) ? Wk : Wv);
            const float* Wp = W + ((wn & 3) * 16 + l15) * 128 + ks * 32 + quad * 8;
            float4 wa = *(const float4*)Wp;
            float4 wb = *(const float4*)(Wp + 4);
            bf16x8 bf;
            bf[0] = (__bf16)wa.x; bf[1] = (__bf16)wa.y;
            bf[2] = (__bf16)wa.z; bf[3] = (__bf16)wa.w;
            bf[4] = (__bf16)wb.x; bf[5] = (__bf16)wb.y;
            bf[6] = (__bf16)wb.z; bf[7] = (__bf16)wb.w;
            acc[j] = MFMA32(af, bf, acc[j]);            // D[m=tok][n=out]
        }
    }

    // epilogue: D rows (quad*4+r) = token, col l15 = output within n-tile
    #pragma unroll
    for (int j = 0; j < 3; ++j) {
        const int wn   = w * 3 + j;
        const int msel = wn >> 2;
        const int o0   = (wn & 3) * 16;
        const float* bb = (msel == 0) ? bq : ((msel == 1) ? bk : bv);
        float bias = bb[o0 + l15];
        if (msel < 2) {
            // Q at cols [0,64), K at cols [64,128) of os
            const float scl = (msel == 0) ? QSCALE : 1.0f;
            const int oc = wn * 16 + l15;               // 0..127
            #pragma unroll
            for (int r = 0; r < 4; ++r)
                os[(quad * 4 + r) * 144 + oc] = (__bf16)((acc[j][r] + bias) * scl);
        } else {
            // permuted V store: token l0+quad*4+r -> tile kt, kc fixed per
            // block, quad_v == quad, i == r.
            const int d  = o0 + l15;
            const int kt = l0 >> 6;
            const int kc = (l0 >> 4) & 3;
            bf16x4 v;
            #pragma unroll
            for (int r = 0; r < 4; ++r) v[r] = (__bf16)(acc[j][r] + bias);
            *(bf16x4*)(VTws + (size_t)b * 262144 + kt * 4096
                       + d * 64 + quad * 16 + kc * 4) = v;
        }
    }
    __syncthreads();

    // Q store coalesced [l][64]; K store to the MFMA-permuted tile layout.
    // thread t -> token tok = t>>4, 16B chunk c = t&15.
    {
        const int tok = t >> 4, c = t & 15;
        bf16x8 v = *(const bf16x8*)&os[tok * 144 + c * 8];
        if (c < 8) {
            *(bf16x8*)(Qws + ((size_t)(b * 4096 + l0 + tok)) * 64 + c * 8) = v;
        } else {
            const int d8 = c - 8;                       // d = d8*8 .. +7
            __bf16* dst = Kws + (size_t)b * 262144
                + (l0 >> 6) * 4096            // tile
                + ((l0 >> 4) & 3) * 1024      // nt subtile
                + (d8 >> 2) * 512             // half = d>>5
                + (d8 & 3) * 128              // quad = (d>>3)&3
                + tok * 8;                    // l15 = key&15
            *(bf16x8*)dst = v;
        }
    }
}

// ---------------------------------------------------------------------------
// Kernel 2: flash attention, split-K, fixed-bound softmax (no online max).
// K fragments direct from global in MFMA-permuted layout (coalesced 1KB
// instructions, prefetched one tile ahead into a second register set; 4
// waves/block share the tile -> L1 hits). LDS stages only V (double-buffered
// global_load_lds, XOR-swizzled, b128 reads). PV via mfma 16x16x16bf16_1k
// (B-layout == QK C-layout; no P transpose). Partial ctx bf16 via LDS
// transpose -> coalesced 16B full-line stores.
// grid = SPLIT x 256; block = 64 q (wave owns 16), 16 k-tiles of 64 keys.
// ---------------------------------------------------------------------------
__global__ __launch_bounds__(256, 4) void attn_kernel(
    const __bf16* __restrict__ Qws, const __bf16* __restrict__ Kws,
    const __bf16* __restrict__ VTws,
    __bf16* __restrict__ Ops, float* __restrict__ Lws)
{
    // V only: slots of 16B, [d][chunk^(d&7)] (permuted layout), 2 x 8 KB
    __shared__ __align__(16) __bf16 sbuf[2][4096];

    const int bid   = blockIdx.x;
    const int split = bid >> 8;
    const int qt    = bid & 255;
    const int b  = qt >> 6;
    const int l0 = (qt & 63) << 6;
    const int t    = threadIdx.x;
    const int w    = t >> 6;
    const int lane = t & 63;
    const int quad = lane >> 4;
    const int l15  = lane & 15;

    // Q fragments (q = l15), pre-scaled by 0.125*log2e
    const __bf16* qptr = Qws + ((size_t)(b * 4096 + l0 + w * 16 + l15)) * 64 + quad * 8;
    bf16x8 qf0 = *(const bf16x8*)qptr;
    bf16x8 qf1 = *(const bf16x8*)(qptr + 32);

    f32x4 cfr[4];
    #pragma unroll
    for (int mt = 0; mt < 4; ++mt)
        #pragma unroll
        for (int r = 0; r < 4; ++r) cfr[mt][r] = 0.f;
    float l_run = 0.f;

    // hoisted V LDS element offsets (loop-invariant across tiles)
    int voff[8];
    #pragma unroll
    for (int mt = 0; mt < 4; ++mt) {
        const int d = mt * 16 + l15;
        #pragma unroll
        for (int kc8 = 0; kc8 < 2; ++kc8)
            voff[kc8 * 4 + mt] = d * 64 + (((2 * quad + kc8) ^ (d & 7)) * 8);
    }

    // V staging source pointer (swizzled 16B chunks)
    const uint4* Vg = (const uint4*)(VTws + ((size_t)b << 18));
    const int rw = t >> 3, cw = (t & 7) ^ ((t >> 3) & 7);
    const uint4* vp = Vg + rw * 8 + cw + split * 8192;

    // K direct-global, permuted layout: per-lane offset lane*8 (coalesced)
    const __bf16* Kgl = Kws + ((size_t)b << 18)
                      + (size_t)(split * 16) * 4096 + lane * 8;

    union B4 { bf16x4 h; s16x4 s; };
    union V8 { bf16x8 v; s16x4 q[2]; };

    auto stageV = [&](__bf16* Bb) {
        GL16(vp,       Bb +        w * 512);
        GL16(vp + 256, Bb + 2048 + w * 512);
        vp += 512;
    };

    bf16x8 kfA[4][2], kfB[4][2];
    auto loadK = [&](bf16x8 (*kf)[2], int kt) {
        const __bf16* p = Kgl + (size_t)kt * 4096;
        #pragma unroll
        for (int nt = 0; nt < 4; ++nt) {
            kf[nt][0] = *(const bf16x8*)(p + nt * 1024);
            kf[nt][1] = *(const bf16x8*)(p + nt * 1024 + 512);
        }
    };

    auto tile_step = [&](const __bf16* __restrict__ B, bf16x8 (*kf)[2]) {
        // ---- QK^T (A=K from regs, B=Q), C init = -BBOUND, p = exp2(s) -----
        B4 pk[4];                      // P in C-layout == B-layout of 16x16x16
        float ps[4];
        #pragma unroll
        for (int nt = 0; nt < 4; ++nt) {
            f32x4 a = {-BBOUND, -BBOUND, -BBOUND, -BBOUND};
            a = MFMA32(kf[nt][0], qf0, a);
            a = MFMA32(kf[nt][1], qf1, a);
            float p0 = EXP2F(a[0]), p1 = EXP2F(a[1]);
            float p2 = EXP2F(a[2]), p3 = EXP2F(a[3]);
            pk[nt].h[0] = (__bf16)p0; pk[nt].h[1] = (__bf16)p1;
            pk[nt].h[2] = (__bf16)p2; pk[nt].h[3] = (__bf16)p3;
            ps[nt] = (p0 + p1) + (p2 + p3);
        }
        float psum = (ps[0] + ps[1]) + (ps[2] + ps[3]);
        psum += __shfl_xor(psum, 16);
        psum += __shfl_xor(psum, 32);
        l_run += psum;

        // ---- PV: ctx^T += V^T · P^T (b128 V reads, two MFMAs per read) ----
        #pragma unroll
        for (int kc8 = 0; kc8 < 2; ++kc8) {
            #pragma unroll
            for (int mt = 0; mt < 4; ++mt) {
                V8 vv;
                vv.v = *(const bf16x8*)&B[voff[kc8 * 4 + mt]];
                cfr[mt] = MFMA16K(vv.q[0], pk[2 * kc8 + 0].s, cfr[mt]);
                cfr[mt] = MFMA16K(vv.q[1], pk[2 * kc8 + 1].s, cfr[mt]);
            }
        }
    };

    // prologue: V tile 0 -> buffer 0; K frags tile 0 -> regs
    stageV(sbuf[0]);
    loadK(kfA, 0);

    for (int kt2 = 0; kt2 < 8; ++kt2) {
        __syncthreads();               // V buffer 0 ready (vmcnt drained)
        stageV(sbuf[1]);               // prefetch odd V tile
        loadK(kfB, 2 * kt2 + 1);       // prefetch odd K frags (used next step)
        tile_step(sbuf[0], kfA);
        __syncthreads();               // V buffer 1 ready
        if (kt2 < 7) {
            stageV(sbuf[0]);
            loadK(kfA, 2 * kt2 + 2);
        }
        tile_step(sbuf[1], kfB);
    }
    __syncthreads();                   // sbuf free for epilogue transpose

    // epilogue: transpose ctx through LDS so partial ctx goes out as
    // coalesced bf16 16B stores (full 128B lines per row).
    {
        __bf16* tb = (__bf16*)sbuf + w * 1088;     // 16 rows x stride 68
        #pragma unroll
        for (int mt = 0; mt < 4; ++mt) {
            bf16x4 v;
            #pragma unroll
            for (int r = 0; r < 4; ++r) v[r] = (__bf16)cfr[mt][r];
            *(bf16x4*)&tb[l15 * 68 + mt * 16 + quad * 4] = v;
        }
        const int rowbase = (split * 4 + b) * 4096 + l0 + w * 16;
        #pragma unroll
        for (int h = 0; h < 2; ++h) {
            const int chunk = lane + h * 64;       // 0..127
            const int tok = chunk >> 3, c8 = chunk & 7;
            bf16x8 v = *(const bf16x8*)&tb[tok * 68 + c8 * 8];
            *(bf16x8*)(Ops + (size_t)(rowbase + tok) * 64 + c8 * 8) = v;
        }
        if (quad == 0) Lws[rowbase + l15] = l_run;
    }
}

// ---------------------------------------------------------------------------
// Kernel 3: split-combine (pure sum, bf16 partials) + output projection
// (bf16 MFMA) + bias + residual. grid = 1024 (b x 256 x 16 tok).
// ---------------------------------------------------------------------------
__global__ __launch_bounds__(256) void outproj_kernel(
    const float* __restrict__ inpt,
    const __bf16* __restrict__ Ops, const float* __restrict__ Lws,
    const float* __restrict__ Wo, const float* __restrict__ bo,
    float* __restrict__ out)
{
    __shared__ __align__(16) __bf16 cx[16 * 72];    // combined ctx [tok][d]
    const int bid = blockIdx.x;
    const int b   = bid >> 8;
    const int l0  = (bid & 255) << 4;
    const int t   = threadIdx.x;

    // combine: thread (token = t>>4, d4 = (t&15)*4); partials sum directly
    {
        const int token = t >> 4, d4 = (t & 15) << 2;
        const int rowb  = b * 4096 + l0 + token;
        float denom = 0.f;
        #pragma unroll
        for (int s = 0; s < SPLIT; ++s) denom += Lws[s * 16384 + rowb];
        const float inv = 1.f / denom;
        float ax = 0.f, ay = 0.f, az = 0.f, aw = 0.f;
        #pragma unroll
        for (int s = 0; s < SPLIT; ++s) {
            const bf16x4 v = *(const bf16x4*)(Ops
                + ((size_t)(s * 16384 + rowb)) * 64 + d4);
            ax += (float)v[0]; ay += (float)v[1];
            az += (float)v[2]; aw += (float)v[3];
        }
        bf16x4 pv;
        pv[0] = (__bf16)(ax * inv); pv[1] = (__bf16)(ay * inv);
        pv[2] = (__bf16)(az * inv); pv[3] = (__bf16)(aw * inv);
        *(bf16x4*)&cx[token * 72 + d4] = pv;
    }
    __syncthreads();

    const int w    = t >> 6;
    const int lane = t & 63;
    const int quad = lane >> 4;
    const int l15  = lane & 15;

    f32x4 acc[2];
    #pragma unroll
    for (int mi = 0; mi < 2; ++mi)
        #pragma unroll
        for (int r = 0; r < 4; ++r) acc[mi][r] = 0.f;

    #pragma unroll
    for (int ks = 0; ks < 2; ++ks) {
        bf16x8 bfrag = *(const bf16x8*)&cx[l15 * 72 + ks * 32 + quad * 8];  // B[n=tok][k=d]
        #pragma unroll
        for (int mi = 0; mi < 2; ++mi) {
            const int crow = (w * 2 + mi) * 16 + l15;
            const float* Wp = Wo + crow * 64 + ks * 32 + quad * 8;
            float4 wa = *(const float4*)Wp;
            float4 wb = *(const float4*)(Wp + 4);
            bf16x8 afrag;
            afrag[0] = (__bf16)wa.x; afrag[1] = (__bf16)wa.y;
            afrag[2] = (__bf16)wa.z; afrag[3] = (__bf16)wa.w;
            afrag[4] = (__bf16)wb.x; afrag[5] = (__bf16)wb.y;
            afrag[6] = (__bf16)wb.z; afrag[7] = (__bf16)wb.w;
            acc[mi] = MFMA32(afrag, bfrag, acc[mi]);     // D[m=c][n=tok]
        }
    }

    // epilogue: rows (quad*4+r) = c offset, col l15 = token
    #pragma unroll
    for (int mi = 0; mi < 2; ++mi) {
        #pragma unroll
        for (int r = 0; r < 4; ++r) {
            const int c = (w * 2 + mi) * 16 + quad * 4 + r;
            const size_t addr = ((size_t)(b * 128 + c)) * 4096 + l0 + l15;
            out[addr] = inpt[addr] + bo[c] + acc[mi][r];
        }
    }
}

// ---------------------------------------------------------------------------
extern "C" void kernel_launch(void* const* d_in, const int* in_sizes, int n_in,
                              void* d_out, int out_size, void* d_ws, size_t ws_size,
                              hipStream_t stream)
{
    const float* inpt = (const float*)d_in[0];
    const float* Wq   = (const float*)d_in[1];
    const float* bq   = (const float*)d_in[2];
    const float* Wk   = (const float*)d_in[3];
    const float* bk   = (const float*)d_in[4];
    const float* Wv   = (const float*)d_in[5];
    const float* bv   = (const float*)d_in[6];
    const float* Wo   = (const float*)d_in[7];
    const float* bo   = (const float*)d_in[8];
    float* out = (float*)d_out;

    char* ws = (char*)d_ws;
    const size_t MB = (size_t)1 << 20;
    __bf16* Qws  = (__bf16*)(ws + 0 * MB);
    __bf16* Kws  = (__bf16*)(ws + 2 * MB);         // MFMA-permuted tile layout
    __bf16* VTws = (__bf16*)(ws + 4 * MB);         // permuted tile layout
    __bf16* Ops  = (__bf16*)(ws + 6 * MB);         // SPLIT(4) x 2.1MB = 8.4 MB
    float*  Lws  = (float*)(ws + 16 * MB);         // 256 KB

    qkv_kernel<<<1024, 256, 0, stream>>>(inpt, Wq, bq, Wk, bk, Wv, bv, Qws, Kws, VTws);
    attn_kernel<<<SPLIT * 256, 256, 0, stream>>>(Qws, Kws, VTws, Ops, Lws);
    outproj_kernel<<<1024, 256, 0, stream>>>(inpt, Ops, Lws, Wo, bo, out);
}